// Round 1
// baseline (1214.975 us; speedup 1.0000x reference)
//
#include <hip/hip_runtime.h>
#include <hip/hip_fp16.h>

typedef unsigned short u16;
typedef _Float16 f16;
typedef __attribute__((ext_vector_type(4))) u16 u16x4;
typedef __attribute__((ext_vector_type(8))) f16 f16x8;
typedef __attribute__((ext_vector_type(4))) float f32x4;

#define BATCH   2048
#define IN_DIM  376
#define KPAD0   384
#define HIDDEN  1024
#define OUT_DIM 17

// ---- workspace layout (bytes) ---- (kept identical to previous version)
#define WS_Z     0
#define WS_X16   1024
#define WS_ACC16 (WS_X16 + (size_t)BATCH*KPAD0*2)            // 4 f16 bufs (nodes 1..4)
#define WS_ACCF  (WS_ACC16 + (size_t)4*BATCH*HIDDEN*2)       // f32 buf (node 5 only now)
#define WS_W0T   (WS_ACCF + (size_t)5*BATCH*HIDDEN*4)
#define WS_WHT   (WS_W0T + (size_t)20*HIDDEN*KPAD0*2)

__device__ __constant__ int D_PREF[5] = {0, 0, 4, 7, 9};

__device__ inline void gll16(const void* g, void* l) {
    __builtin_amdgcn_global_load_lds(
        (const __attribute__((address_space(1))) unsigned int*)g,
        (__attribute__((address_space(3))) unsigned int*)l, 16, 0, 0);
}

// ---------------- z = softmax((log_alphas + eps)/tau) ----------------
__global__ void z_kernel(const float* __restrict__ la, const float* __restrict__ ep,
                         float* __restrict__ z) {
    int t = threadIdx.x;
    if (t >= 30) return;
    float v[5]; float mx = -1e30f;
    #pragma unroll
    for (int o = 0; o < 5; ++o) { v[o] = la[t*5+o] + ep[t*5+o]; mx = fmaxf(mx, v[o]); }
    float s = 0.f;
    #pragma unroll
    for (int o = 0; o < 5; ++o) { v[o] = expf(v[o] - mx); s += v[o]; }
    float inv = 1.f / s;
    #pragma unroll
    for (int o = 0; o < 5; ++o) z[t*5+o] = v[o] * inv;
}

// ---------------- x f32 [2048][376] -> f16 [2048][384] zero-padded ----------------
__global__ void xcvt_kernel(const float* __restrict__ x, u16* __restrict__ x16) {
    int idx = blockIdx.x * 256 + threadIdx.x;
    int b = idx / KPAD0, c = idx % KPAD0;
    float v = (c < IN_DIM) ? x[(size_t)b*IN_DIM + c] : 0.f;
    f16 h = (f16)v;
    x16[idx] = __builtin_bit_cast(u16, h);
}

// ---------------- merged W0 + Wh transpose -> f16 [n][k] ----------------
// blocks [0,1920): W0 slices -> [1024][384];  blocks [1920,12160): Wh slices -> [1024][1024]
__global__ void wtrans_kernel(const float* __restrict__ W0, const float* __restrict__ Wh,
                              u16* __restrict__ dst0, u16* __restrict__ dstH) {
    __shared__ u16 sT[64*68];
    int bid = blockIdx.x;
    int t = threadIdx.x;
    if (bid < 1920) {
        int mat = bid / 96, rem = bid % 96;
        int kt = rem / 16, nt = rem % 16;
        int i = mat / 4 + 1, o = mat % 4;
        const float* src = W0 + (size_t)(i*5 + o) * IN_DIM * HIDDEN;
        #pragma unroll
        for (int p = 0; p < 16; ++p) {
            int e = p*256 + t;
            int kr = e >> 6, nc = e & 63;
            int k = kt*64 + kr;
            float v = (k < IN_DIM) ? src[(size_t)k*HIDDEN + nt*64 + nc] : 0.f;
            f16 h = (f16)v;
            sT[nc*68 + kr] = __builtin_bit_cast(u16, h);
        }
        __syncthreads();
        u16* d = dst0 + (size_t)mat * HIDDEN * KPAD0;
        #pragma unroll
        for (int p = 0; p < 4; ++p) {
            int c = p*256 + t;
            int nc = c >> 4, k4 = (c & 15) * 4;
            u16x4 v;
            #pragma unroll
            for (int j = 0; j < 4; ++j) v[j] = sT[nc*68 + k4 + j];
            *(u16x4*)&d[(size_t)(nt*64 + nc)*KPAD0 + kt*64 + k4] = v;
        }
    } else {
        const int SK[10] = {1,1,1,1,2,2,2,3,3,4};
        const int SI[10] = {2,3,4,5,3,4,5,4,5,5};
        int bid2 = bid - 1920;
        int mat = bid2 >> 8, rem = bid2 & 255;
        int kt = rem / 16, nt = rem % 16;
        int e = mat / 4, o = mat % 4;
        const float* src = Wh + (size_t)(((SK[e]-1)*6 + SI[e])*5 + o) * HIDDEN * HIDDEN;
        #pragma unroll
        for (int p = 0; p < 16; ++p) {
            int ee = p*256 + t;
            int kr = ee >> 6, nc = ee & 63;
            float v = src[(size_t)(kt*64 + kr)*HIDDEN + nt*64 + nc];
            f16 h = (f16)v;
            sT[nc*68 + kr] = __builtin_bit_cast(u16, h);
        }
        __syncthreads();
        u16* d = dstH + (size_t)mat * HIDDEN * HIDDEN;
        #pragma unroll
        for (int p = 0; p < 4; ++p) {
            int c = p*256 + t;
            int nc = c >> 4, k4 = (c & 15) * 4;
            u16x4 v;
            #pragma unroll
            for (int j = 0; j < 4; ++j) v[j] = sT[nc*68 + k4 + j];
            *(u16x4*)&d[(size_t)(nt*64 + nc)*HIDDEN + kt*64 + k4] = v;
        }
    }
}

// ---------------- fused node kernel: all incoming edges of node `stepi` ----------------
// Grid: 512 blocks = 32 m-tiles x 16 n-tiles, XCD-swizzled (all 32 m-blocks of one
// n-tile on ONE XCD -> B panel stays in that L2). Each block loops over the i edges,
// software-pipelined 2-deep across edge boundaries (stage tile t+1 while computing t).
// Per-edge epilogue (bias + activation + z-mix) is in-register; NO atomics.
__global__ __launch_bounds__(256)
void step_kernel(int stepi,
                 const u16* __restrict__ x16, const u16* __restrict__ acc16,
                 u16* __restrict__ acc16out, float* __restrict__ accf5,
                 const u16* __restrict__ w0t, const u16* __restrict__ wht,
                 const float* __restrict__ b0, const float* __restrict__ bh,
                 const float* __restrict__ zws) {
    __shared__ alignas(16) u16 sA[2][64*64];
    __shared__ alignas(16) u16 sB[2][4][64*64];
    const int t = threadIdx.x;
    const int lane = t & 63, wid = t >> 6;
    const int l15 = lane & 15, lk = lane >> 4;

    const int bid  = blockIdx.x;
    const int slot = bid & 7;
    const int q    = bid >> 3;
    const int m0   = (q & 31) * 64;
    const int n0   = ((q >> 5) * 8 + slot) * 64;

    // staging lane geometry: lane L -> row_in_chunk = L>>3, LDS slot = L&7,
    // fetch global chunk sc = (L&7) ^ (L>>3)   (XOR swizzle for conflict-free reads)
    const int srow = lane >> 3;
    const int sc   = (lane & 7) ^ srow;

    // --- staging pointer state (edge currently being staged) ---
    const u16* aG0; const u16* aG1; const u16* bG[8]; int snks;
    auto setup = [&](int k) {
        const u16* Ap; int ldA; const u16* Wt; int ldW;
        if (k == 0) {
            Ap = x16; ldA = KPAD0; snks = KPAD0/64;
            Wt = w0t + (size_t)((stepi-1)*4) * HIDDEN * KPAD0; ldW = KPAD0;
        } else {
            Ap = acc16 + (size_t)(k-1) * BATCH * HIDDEN; ldA = HIDDEN; snks = HIDDEN/64;
            int eidx = D_PREF[k] + (stepi - k - 1);
            Wt = wht + (size_t)(eidx*4) * HIDDEN * HIDDEN; ldW = HIDDEN;
        }
        aG0 = Ap + (size_t)(m0 + wid*16 + srow)     * ldA + sc*8;
        aG1 = Ap + (size_t)(m0 + wid*16 + 8 + srow) * ldA + sc*8;
        const u16* Wop = Wt + (size_t)wid * HIDDEN * ldW;
        #pragma unroll
        for (int p = 0; p < 8; ++p)
            bG[p] = Wop + (size_t)(n0 + p*8 + srow) * ldW + sc*8;
    };
    auto stage = [&](int buf, int kb) {
        const int koff = kb * 64;
        gll16(aG0 + koff, &sA[buf][(wid*2)   * 512]);
        gll16(aG1 + koff, &sA[buf][(wid*2+1) * 512]);
        #pragma unroll
        for (int p = 0; p < 8; ++p)
            gll16(bG[p] + koff, &sB[buf][wid][p*512]);
    };

    f32x4 acc[4][4] = {};     // [mfrag][op], reset per edge
    float outv[4][4] = {};    // z-mixed running sum over edges
    const int colw = n0 + wid*16 + l15;

    // prologue: stage first tile of edge 0
    setup(0);
    stage(0, 0);
    int sk = 0, skb = 1;      // next tile to stage = (sk, skb)
    int cur = 0;
    __syncthreads();

    for (int ck = 0; ck < stepi; ++ck) {
        const int nk = (ck == 0) ? (KPAD0/64) : (HIDDEN/64);
        for (int kb = 0; kb < nk; ++kb) {
            // issue next tile's stage (possibly crossing into the next edge)
            if (skb == snks) { sk++; skb = 0; if (sk < stepi) setup(sk); }
            if (sk < stepi) { stage(cur ^ 1, skb); skb++; }

            // compute current tile from buf[cur]
            #pragma unroll
            for (int kc = 0; kc < 2; ++kc) {
                f16x8 af[4], bf[4];
                #pragma unroll
                for (int f = 0; f < 4; ++f) {
                    int row = f*16 + l15;
                    int cc = (kc*4 + lk) ^ (row & 7);
                    af[f] = *(const f16x8*)&sA[cur][row*64 + cc*8];
                }
                #pragma unroll
                for (int o = 0; o < 4; ++o) {
                    int row = wid*16 + l15;
                    int cc = (kc*4 + lk) ^ (row & 7);
                    bf[o] = *(const f16x8*)&sB[cur][o][row*64 + cc*8];
                }
                #pragma unroll
                for (int o = 0; o < 4; ++o)
                    #pragma unroll
                    for (int f = 0; f < 4; ++f)
                        acc[f][o] = __builtin_amdgcn_mfma_f32_16x16x32_f16(af[f], bf[o], acc[f][o], 0, 0, 0);
            }

            // per-edge epilogue: bias + activation + z-mix, in registers
            if (kb == nk - 1) {
                const float* zp   = zws + (ck*6 + stepi)*5;
                const float* bias = (ck == 0)
                    ? b0 + (size_t)(stepi*5) * HIDDEN
                    : bh + (size_t)(((ck-1)*6 + stepi)*5) * HIDDEN;
                #pragma unroll
                for (int o = 0; o < 4; ++o) {
                    float zv = zp[o];
                    float bv = bias[(size_t)o*HIDDEN + colw];
                    #pragma unroll
                    for (int f = 0; f < 4; ++f)
                        #pragma unroll
                        for (int r = 0; r < 4; ++r) {
                            float pre = acc[f][o][r] + bv;
                            float a;
                            if      (o == 0) a = tanhf(pre);
                            else if (o == 1) a = fmaxf(pre, 0.f);
                            else if (o == 2) a = (pre > 0.f) ? pre : expm1f(pre);
                            else             a = (pre > 0.f) ? pre : 0.01f * pre;
                            outv[f][r] += zv * a;
                            acc[f][o][r] = 0.f;
                        }
                }
            }
            __syncthreads();
            cur ^= 1;
        }
    }

    // store node output: f16 (A for later steps) or f32 (node 5, feeds out_kernel)
    if (stepi < 5) {
        #pragma unroll
        for (int f = 0; f < 4; ++f)
            #pragma unroll
            for (int r = 0; r < 4; ++r) {
                f16 h = (f16)outv[f][r];
                acc16out[(size_t)(m0 + f*16 + lk*4 + r)*HIDDEN + colw] = __builtin_bit_cast(u16, h);
            }
    } else {
        #pragma unroll
        for (int f = 0; f < 4; ++f)
            #pragma unroll
            for (int r = 0; r < 4; ++r)
                accf5[(size_t)(m0 + f*16 + lk*4 + r)*HIDDEN + colw] = outv[f][r];
    }
}

// ---------------- out = tanh(acc5_f32 @ Wout + bout) ----------------
__global__ void out_kernel(const float* __restrict__ acc5, const float* __restrict__ Wout,
                           const float* __restrict__ bout, float* __restrict__ out) {
    int t = threadIdx.x;
    int g = t & 15, rl = t >> 4;
    int row = blockIdx.x * 16 + rl;
    const float* a = acc5 + (size_t)row * HIDDEN;
    float s[OUT_DIM] = {};
    for (int kk = 0; kk < HIDDEN/16; ++kk) {
        int kidx = kk*16 + g;
        float av = a[kidx];
        const float* wr = Wout + (size_t)kidx * OUT_DIM;
        #pragma unroll
        for (int j = 0; j < OUT_DIM; ++j) s[j] += av * wr[j];
    }
    #pragma unroll
    for (int m = 1; m < 16; m <<= 1) {
        #pragma unroll
        for (int j = 0; j < OUT_DIM; ++j) s[j] += __shfl_xor(s[j], m, 64);
    }
    if (g == 0) {
        #pragma unroll
        for (int j = 0; j < OUT_DIM; ++j)
            out[(size_t)row*OUT_DIM + j] = tanhf(s[j] + bout[j]);
    }
}

extern "C" void kernel_launch(void* const* d_in, const int* in_sizes, int n_in,
                              void* d_out, int out_size, void* d_ws, size_t ws_size,
                              hipStream_t stream) {
    const float* x    = (const float*)d_in[0];
    const float* W0   = (const float*)d_in[1];
    const float* b0   = (const float*)d_in[2];
    const float* Wh   = (const float*)d_in[3];
    const float* bh   = (const float*)d_in[4];
    const float* Wout = (const float*)d_in[5];
    const float* bout = (const float*)d_in[6];
    const float* la   = (const float*)d_in[7];
    const float* eps  = (const float*)d_in[8];
    float* out = (float*)d_out;

    char* ws = (char*)d_ws;
    float* zws  = (float*)(ws + WS_Z);
    u16* x16    = (u16*)(ws + WS_X16);
    u16* acc16  = (u16*)(ws + WS_ACC16);
    float* accf = (float*)(ws + WS_ACCF);
    u16* w0t    = (u16*)(ws + WS_W0T);
    u16* wht    = (u16*)(ws + WS_WHT);

    z_kernel<<<1, 32, 0, stream>>>(la, eps, zws);
    xcvt_kernel<<<(BATCH*KPAD0)/256, 256, 0, stream>>>(x, x16);
    wtrans_kernel<<<1920 + 10240, 256, 0, stream>>>(W0, Wh, w0t, wht);

    for (int i = 1; i <= 5; ++i) {
        u16* a16o = acc16 + (size_t)(i-1)*BATCH*HIDDEN;   // unused for i==5
        step_kernel<<<512, 256, 0, stream>>>(
            i, x16, acc16, a16o, accf, w0t, wht, b0, bh, zws);
    }
    out_kernel<<<BATCH/16, 256, 0, stream>>>(accf, Wout, bout, out);
}

// Round 2
// 924.869 us; speedup vs baseline: 1.3137x; 1.3137x over previous
//
#include <hip/hip_runtime.h>
#include <hip/hip_fp16.h>

typedef unsigned short u16;
typedef _Float16 f16;
typedef __attribute__((ext_vector_type(4))) u16 u16x4;
typedef __attribute__((ext_vector_type(8))) f16 f16x8;
typedef __attribute__((ext_vector_type(4))) float f32x4;

#define BATCH   2048
#define IN_DIM  376
#define KPAD0   384
#define HIDDEN  1024
#define OUT_DIM 17

// ---- workspace layout (bytes) ----
#define WS_Z     0
#define WS_X16   1024
#define WS_ACC16 (WS_X16 + (size_t)BATCH*KPAD0*2)            // 4 f16 bufs (nodes 1..4)
#define WS_ACCF  (WS_ACC16 + (size_t)4*BATCH*HIDDEN*2)       // f32 buf (node 5)
#define WS_W0T   (WS_ACCF + (size_t)5*BATCH*HIDDEN*4)
#define WS_WHT   (WS_W0T + (size_t)20*HIDDEN*KPAD0*2)

__device__ __constant__ int D_PREF[5] = {0, 0, 4, 7, 9};

__device__ inline void gll16(const void* g, void* l) {
    __builtin_amdgcn_global_load_lds(
        (const __attribute__((address_space(1))) unsigned int*)g,
        (__attribute__((address_space(3))) unsigned int*)l, 16, 0, 0);
}

// ---------------- z = softmax((log_alphas + eps)/tau) ----------------
__global__ void z_kernel(const float* __restrict__ la, const float* __restrict__ ep,
                         float* __restrict__ z) {
    int t = threadIdx.x;
    if (t >= 30) return;
    float v[5]; float mx = -1e30f;
    #pragma unroll
    for (int o = 0; o < 5; ++o) { v[o] = la[t*5+o] + ep[t*5+o]; mx = fmaxf(mx, v[o]); }
    float s = 0.f;
    #pragma unroll
    for (int o = 0; o < 5; ++o) { v[o] = expf(v[o] - mx); s += v[o]; }
    float inv = 1.f / s;
    #pragma unroll
    for (int o = 0; o < 5; ++o) z[t*5+o] = v[o] * inv;
}

// ---------------- x f32 [2048][376] -> f16 [2048][384] zero-padded ----------------
__global__ void xcvt_kernel(const float* __restrict__ x, u16* __restrict__ x16) {
    int idx = blockIdx.x * 256 + threadIdx.x;
    int b = idx / KPAD0, c = idx % KPAD0;
    float v = (c < IN_DIM) ? x[(size_t)b*IN_DIM + c] : 0.f;
    f16 h = (f16)v;
    x16[idx] = __builtin_bit_cast(u16, h);
}

// ---------------- merged W0 + Wh transpose -> f16 [n][k] ----------------
// blocks [0,1920): W0 slices -> [1024][384];  blocks [1920,12160): Wh slices -> [1024][1024]
__global__ void wtrans_kernel(const float* __restrict__ W0, const float* __restrict__ Wh,
                              u16* __restrict__ dst0, u16* __restrict__ dstH) {
    __shared__ u16 sT[64*68];
    int bid = blockIdx.x;
    int t = threadIdx.x;
    if (bid < 1920) {
        int mat = bid / 96, rem = bid % 96;
        int kt = rem / 16, nt = rem % 16;
        int i = mat / 4 + 1, o = mat % 4;
        const float* src = W0 + (size_t)(i*5 + o) * IN_DIM * HIDDEN;
        #pragma unroll
        for (int p = 0; p < 16; ++p) {
            int e = p*256 + t;
            int kr = e >> 6, nc = e & 63;
            int k = kt*64 + kr;
            float v = (k < IN_DIM) ? src[(size_t)k*HIDDEN + nt*64 + nc] : 0.f;
            f16 h = (f16)v;
            sT[nc*68 + kr] = __builtin_bit_cast(u16, h);
        }
        __syncthreads();
        u16* d = dst0 + (size_t)mat * HIDDEN * KPAD0;
        #pragma unroll
        for (int p = 0; p < 4; ++p) {
            int c = p*256 + t;
            int nc = c >> 4, k4 = (c & 15) * 4;
            u16x4 v;
            #pragma unroll
            for (int j = 0; j < 4; ++j) v[j] = sT[nc*68 + k4 + j];
            *(u16x4*)&d[(size_t)(nt*64 + nc)*KPAD0 + kt*64 + k4] = v;
        }
    } else {
        const int SK[10] = {1,1,1,1,2,2,2,3,3,4};
        const int SI[10] = {2,3,4,5,3,4,5,4,5,5};
        int bid2 = bid - 1920;
        int mat = bid2 >> 8, rem = bid2 & 255;
        int kt = rem / 16, nt = rem % 16;
        int e = mat / 4, o = mat % 4;
        const float* src = Wh + (size_t)(((SK[e]-1)*6 + SI[e])*5 + o) * HIDDEN * HIDDEN;
        #pragma unroll
        for (int p = 0; p < 16; ++p) {
            int ee = p*256 + t;
            int kr = ee >> 6, nc = ee & 63;
            float v = src[(size_t)(kt*64 + kr)*HIDDEN + nt*64 + nc];
            f16 h = (f16)v;
            sT[nc*68 + kr] = __builtin_bit_cast(u16, h);
        }
        __syncthreads();
        u16* d = dstH + (size_t)mat * HIDDEN * HIDDEN;
        #pragma unroll
        for (int p = 0; p < 4; ++p) {
            int c = p*256 + t;
            int nc = c >> 4, k4 = (c & 15) * 4;
            u16x4 v;
            #pragma unroll
            for (int j = 0; j < 4; ++j) v[j] = sT[nc*68 + k4 + j];
            *(u16x4*)&d[(size_t)(nt*64 + nc)*HIDDEN + kt*64 + k4] = v;
        }
    }
}

// ---------------- fused node kernel: all incoming edges of node `stepi` ----------------
// Tile M=64 x N=32 (x4 ops). LDS = 8KB A + 16KB B = 24KB -> 4+ blocks/CU capacity.
// Grid: 1024 blocks = 32 m-tiles x 32 n-tiles, XCD-swizzled (all 32 m-blocks of one
// n-tile consecutive on ONE XCD -> B panel stays in that L2; A panels L3-resident).
// Wave layout: wid>>1 = m-half (32 rows), wid&1 = n-half (16 cols), all 4 ops per wave.
// Per-edge epilogue (bias + activation + z-mix) in registers; NO atomics, NO cvt pass.
__global__ __launch_bounds__(256, 4)
void step_kernel(int stepi,
                 const u16* __restrict__ x16, const u16* __restrict__ acc16,
                 u16* __restrict__ acc16out, float* __restrict__ accf5,
                 const u16* __restrict__ w0t, const u16* __restrict__ wht,
                 const float* __restrict__ b0, const float* __restrict__ bh,
                 const float* __restrict__ zws) {
    __shared__ alignas(16) u16 sA[64*64];        //  8 KB: A tile 64 rows x 64 k
    __shared__ alignas(16) u16 sB[4][32*64];     // 16 KB: B tile 4 ops x 32 n x 64 k
    const int t = threadIdx.x;
    const int lane = t & 63, wid = t >> 6;
    const int l15 = lane & 15, lk = lane >> 4;
    const int mh = wid >> 1, nh = wid & 1;

    const int bid  = blockIdx.x;
    const int slot = bid & 7;
    const int q    = bid >> 3;
    const int m0   = (q & 31) * 64;
    const int n0   = ((q >> 5) * 8 + slot) * 32;

    // staging lane geometry: lane L -> row_in_chunk = L>>3, LDS slot = L&7,
    // fetch global chunk sc = (L&7) ^ (L>>3)   (XOR swizzle for conflict-free reads)
    const int srow = lane >> 3;
    const int sc   = (lane & 7) ^ srow;

    f32x4 acc[2][4] = {};     // [mfrag][op], reset per edge
    float outv[2][4] = {};    // z-mixed running sum over edges
    const int colw = n0 + nh*16 + l15;

    for (int ck = 0; ck < stepi; ++ck) {
        const u16* Ap; int ldA, nks;
        const u16* Wt; int ldW;
        const float* bias;
        if (ck == 0) {
            Ap = x16; ldA = KPAD0; nks = KPAD0/64;
            Wt = w0t + (size_t)((stepi-1)*4) * HIDDEN * KPAD0; ldW = KPAD0;
            bias = b0 + (size_t)(stepi*5) * HIDDEN;
        } else {
            Ap = acc16 + (size_t)(ck-1) * BATCH * HIDDEN; ldA = HIDDEN; nks = HIDDEN/64;
            int eidx = D_PREF[ck] + (stepi - ck - 1);
            Wt = wht + (size_t)(eidx*4) * HIDDEN * HIDDEN; ldW = HIDDEN;
            bias = bh + (size_t)(((ck-1)*6 + stepi)*5) * HIDDEN;
        }
        // A: 4 waves cover 64 rows (wave wid stages rows wid*16 .. wid*16+15)
        const u16* aG0 = Ap + (size_t)(m0 + wid*16 + srow)     * ldA + sc*8;
        const u16* aG1 = Ap + (size_t)(m0 + wid*16 + 8 + srow) * ldA + sc*8;
        // B: wave wid stages op wid, 32 n-rows
        const u16* Wop = Wt + (size_t)wid * HIDDEN * ldW;
        const u16* bG[4];
        #pragma unroll
        for (int p = 0; p < 4; ++p)
            bG[p] = Wop + (size_t)(n0 + p*8 + srow) * ldW + sc*8;

        for (int kb = 0; kb < nks; ++kb) {
            const int koff = kb * 64;
            gll16(aG0 + koff, &sA[(wid*2)   * 512]);
            gll16(aG1 + koff, &sA[(wid*2+1) * 512]);
            #pragma unroll
            for (int p = 0; p < 4; ++p)
                gll16(bG[p] + koff, &sB[wid][p*512]);
            __syncthreads();
            #pragma unroll
            for (int kc = 0; kc < 2; ++kc) {
                f16x8 af[2], bf[4];
                #pragma unroll
                for (int f = 0; f < 2; ++f) {
                    int row = mh*32 + f*16 + l15;
                    int cc = (kc*4 + lk) ^ (row & 7);
                    af[f] = *(const f16x8*)&sA[row*64 + cc*8];
                }
                #pragma unroll
                for (int o = 0; o < 4; ++o) {
                    int row = nh*16 + l15;
                    int cc = (kc*4 + lk) ^ (row & 7);
                    bf[o] = *(const f16x8*)&sB[o][row*64 + cc*8];
                }
                #pragma unroll
                for (int o = 0; o < 4; ++o)
                    #pragma unroll
                    for (int f = 0; f < 2; ++f)
                        acc[f][o] = __builtin_amdgcn_mfma_f32_16x16x32_f16(af[f], bf[o], acc[f][o], 0, 0, 0);
            }
            __syncthreads();
        }

        // per-edge epilogue: bias + activation + z-mix, in registers
        const float* zp = zws + (ck*6 + stepi)*5;
        #pragma unroll
        for (int o = 0; o < 4; ++o) {
            float zv = zp[o];
            float bv = bias[(size_t)o*HIDDEN + colw];
            #pragma unroll
            for (int f = 0; f < 2; ++f)
                #pragma unroll
                for (int r = 0; r < 4; ++r) {
                    float pre = acc[f][o][r] + bv;
                    float a;
                    if      (o == 0) a = tanhf(pre);
                    else if (o == 1) a = fmaxf(pre, 0.f);
                    else if (o == 2) a = (pre > 0.f) ? pre : expm1f(pre);
                    else             a = (pre > 0.f) ? pre : 0.01f * pre;
                    outv[f][r] += zv * a;
                    acc[f][o][r] = 0.f;
                }
        }
    }

    // store node output: f16 (A for later steps) or f32 (node 5, feeds out_kernel)
    if (stepi < 5) {
        #pragma unroll
        for (int f = 0; f < 2; ++f)
            #pragma unroll
            for (int r = 0; r < 4; ++r) {
                f16 h = (f16)outv[f][r];
                acc16out[(size_t)(m0 + mh*32 + f*16 + lk*4 + r)*HIDDEN + colw] = __builtin_bit_cast(u16, h);
            }
    } else {
        #pragma unroll
        for (int f = 0; f < 2; ++f)
            #pragma unroll
            for (int r = 0; r < 4; ++r)
                accf5[(size_t)(m0 + mh*32 + f*16 + lk*4 + r)*HIDDEN + colw] = outv[f][r];
    }
}

// ---------------- out = tanh(acc5_f32 @ Wout + bout) ----------------
__global__ void out_kernel(const float* __restrict__ acc5, const float* __restrict__ Wout,
                           const float* __restrict__ bout, float* __restrict__ out) {
    int t = threadIdx.x;
    int g = t & 15, rl = t >> 4;
    int row = blockIdx.x * 16 + rl;
    const float* a = acc5 + (size_t)row * HIDDEN;
    float s[OUT_DIM] = {};
    for (int kk = 0; kk < HIDDEN/16; ++kk) {
        int kidx = kk*16 + g;
        float av = a[kidx];
        const float* wr = Wout + (size_t)kidx * OUT_DIM;
        #pragma unroll
        for (int j = 0; j < OUT_DIM; ++j) s[j] += av * wr[j];
    }
    #pragma unroll
    for (int m = 1; m < 16; m <<= 1) {
        #pragma unroll
        for (int j = 0; j < OUT_DIM; ++j) s[j] += __shfl_xor(s[j], m, 64);
    }
    if (g == 0) {
        #pragma unroll
        for (int j = 0; j < OUT_DIM; ++j)
            out[(size_t)row*OUT_DIM + j] = tanhf(s[j] + bout[j]);
    }
}

extern "C" void kernel_launch(void* const* d_in, const int* in_sizes, int n_in,
                              void* d_out, int out_size, void* d_ws, size_t ws_size,
                              hipStream_t stream) {
    const float* x    = (const float*)d_in[0];
    const float* W0   = (const float*)d_in[1];
    const float* b0   = (const float*)d_in[2];
    const float* Wh   = (const float*)d_in[3];
    const float* bh   = (const float*)d_in[4];
    const float* Wout = (const float*)d_in[5];
    const float* bout = (const float*)d_in[6];
    const float* la   = (const float*)d_in[7];
    const float* eps  = (const float*)d_in[8];
    float* out = (float*)d_out;

    char* ws = (char*)d_ws;
    float* zws  = (float*)(ws + WS_Z);
    u16* x16    = (u16*)(ws + WS_X16);
    u16* acc16  = (u16*)(ws + WS_ACC16);
    float* accf = (float*)(ws + WS_ACCF);
    u16* w0t    = (u16*)(ws + WS_W0T);
    u16* wht    = (u16*)(ws + WS_WHT);

    z_kernel<<<1, 32, 0, stream>>>(la, eps, zws);
    xcvt_kernel<<<(BATCH*KPAD0)/256, 256, 0, stream>>>(x, x16);
    wtrans_kernel<<<1920 + 10240, 256, 0, stream>>>(W0, Wh, w0t, wht);

    for (int i = 1; i <= 5; ++i) {
        u16* a16o = acc16 + (size_t)(i-1)*BATCH*HIDDEN;   // unused for i==5
        step_kernel<<<1024, 256, 0, stream>>>(
            i, x16, acc16, a16o, accf, w0t, wht, b0, bh, zws);
    }
    out_kernel<<<BATCH/16, 256, 0, stream>>>(accf, Wout, bout, out);
}

// Round 3
// 895.077 us; speedup vs baseline: 1.3574x; 1.0333x over previous
//
#include <hip/hip_runtime.h>
#include <hip/hip_fp16.h>

typedef unsigned short u16;
typedef _Float16 f16;
typedef __attribute__((ext_vector_type(4))) u16 u16x4;
typedef __attribute__((ext_vector_type(8))) f16 f16x8;
typedef __attribute__((ext_vector_type(4))) float f32x4;

#define BATCH   2048
#define IN_DIM  376
#define KPAD0   384
#define HIDDEN  1024
#define OUT_DIM 17

// ---- workspace layout (bytes) ----
#define WS_Z     0
#define WS_X16   1024
#define WS_ACC16 (WS_X16 + (size_t)BATCH*KPAD0*2)            // 4 f16 bufs (nodes 1..4)
#define WS_ACCF  (WS_ACC16 + (size_t)4*BATCH*HIDDEN*2)       // f32 buf (node 5)
#define WS_W0T   (WS_ACCF + (size_t)5*BATCH*HIDDEN*4)
#define WS_WHT   (WS_W0T + (size_t)20*HIDDEN*KPAD0*2)

__device__ __constant__ int D_PREF[5] = {0, 0, 4, 7, 9};

__device__ inline void gll16(const void* g, void* l) {
    __builtin_amdgcn_global_load_lds(
        (const __attribute__((address_space(1))) unsigned int*)g,
        (__attribute__((address_space(3))) unsigned int*)l, 16, 0, 0);
}

// ---------------- z = softmax((log_alphas + eps)/tau) ----------------
__global__ void z_kernel(const float* __restrict__ la, const float* __restrict__ ep,
                         float* __restrict__ z) {
    int t = threadIdx.x;
    if (t >= 30) return;
    float v[5]; float mx = -1e30f;
    #pragma unroll
    for (int o = 0; o < 5; ++o) { v[o] = la[t*5+o] + ep[t*5+o]; mx = fmaxf(mx, v[o]); }
    float s = 0.f;
    #pragma unroll
    for (int o = 0; o < 5; ++o) { v[o] = expf(v[o] - mx); s += v[o]; }
    float inv = 1.f / s;
    #pragma unroll
    for (int o = 0; o < 5; ++o) z[t*5+o] = v[o] * inv;
}

// ---------------- x f32 [2048][376] -> f16 [2048][384] zero-padded ----------------
__global__ void xcvt_kernel(const float* __restrict__ x, u16* __restrict__ x16) {
    int idx = blockIdx.x * 256 + threadIdx.x;
    int b = idx / KPAD0, c = idx % KPAD0;
    float v = (c < IN_DIM) ? x[(size_t)b*IN_DIM + c] : 0.f;
    f16 h = (f16)v;
    x16[idx] = __builtin_bit_cast(u16, h);
}

// ---------------- merged W0 + Wh transpose -> f16 [n][k] ----------------
// blocks [0,1920): W0 slices -> [1024][384];  blocks [1920,12160): Wh slices -> [1024][1024]
__global__ void wtrans_kernel(const float* __restrict__ W0, const float* __restrict__ Wh,
                              u16* __restrict__ dst0, u16* __restrict__ dstH) {
    __shared__ u16 sT[64*68];
    int bid = blockIdx.x;
    int t = threadIdx.x;
    if (bid < 1920) {
        int mat = bid / 96, rem = bid % 96;
        int kt = rem / 16, nt = rem % 16;
        int i = mat / 4 + 1, o = mat % 4;
        const float* src = W0 + (size_t)(i*5 + o) * IN_DIM * HIDDEN;
        #pragma unroll
        for (int p = 0; p < 16; ++p) {
            int e = p*256 + t;
            int kr = e >> 6, nc = e & 63;
            int k = kt*64 + kr;
            float v = (k < IN_DIM) ? src[(size_t)k*HIDDEN + nt*64 + nc] : 0.f;
            f16 h = (f16)v;
            sT[nc*68 + kr] = __builtin_bit_cast(u16, h);
        }
        __syncthreads();
        u16* d = dst0 + (size_t)mat * HIDDEN * KPAD0;
        #pragma unroll
        for (int p = 0; p < 4; ++p) {
            int c = p*256 + t;
            int nc = c >> 4, k4 = (c & 15) * 4;
            u16x4 v;
            #pragma unroll
            for (int j = 0; j < 4; ++j) v[j] = sT[nc*68 + k4 + j];
            *(u16x4*)&d[(size_t)(nt*64 + nc)*KPAD0 + kt*64 + k4] = v;
        }
    } else {
        const int SK[10] = {1,1,1,1,2,2,2,3,3,4};
        const int SI[10] = {2,3,4,5,3,4,5,4,5,5};
        int bid2 = bid - 1920;
        int mat = bid2 >> 8, rem = bid2 & 255;
        int kt = rem / 16, nt = rem % 16;
        int e = mat / 4, o = mat % 4;
        const float* src = Wh + (size_t)(((SK[e]-1)*6 + SI[e])*5 + o) * HIDDEN * HIDDEN;
        #pragma unroll
        for (int p = 0; p < 16; ++p) {
            int ee = p*256 + t;
            int kr = ee >> 6, nc = ee & 63;
            float v = src[(size_t)(kt*64 + kr)*HIDDEN + nt*64 + nc];
            f16 h = (f16)v;
            sT[nc*68 + kr] = __builtin_bit_cast(u16, h);
        }
        __syncthreads();
        u16* d = dstH + (size_t)mat * HIDDEN * HIDDEN;
        #pragma unroll
        for (int p = 0; p < 4; ++p) {
            int c = p*256 + t;
            int nc = c >> 4, k4 = (c & 15) * 4;
            u16x4 v;
            #pragma unroll
            for (int j = 0; j < 4; ++j) v[j] = sT[nc*68 + k4 + j];
            *(u16x4*)&d[(size_t)(nt*64 + nc)*HIDDEN + kt*64 + k4] = v;
        }
    }
}

// ---------------- fused node kernel: all incoming edges of node `stepi` ----------------
// Tile M=128 x N=32 (x4 ops), BK=64. LDS = 16KB A + 16KB B = 32KB, single-buffered,
// 2-barrier structure. Block = 512 threads (8 waves): grid 512 = 16 m-tiles x 32 n-tiles
// -> 2 blocks/CU x 8 waves = 16 waves/CU (same wave count as the M=64 version, but
// HALF the barrier-drain events: 2.1 MFLOP per K-step instead of 1.05).
// XCD-swizzled: all 16 m-blocks of one n-tile consecutive on ONE XCD (B panel in L2).
// Wave layout: mq=wid&3 owns 32 m-rows (2 frags), nh=wid>>2 owns 16 of 32 n-cols,
// every wave computes all 4 ops for its cells -> z-mix epilogue fully in-register.
__global__ __launch_bounds__(512, 4)
void step_kernel(int stepi,
                 const u16* __restrict__ x16, const u16* __restrict__ acc16,
                 u16* __restrict__ acc16out, float* __restrict__ accf5,
                 const u16* __restrict__ w0t, const u16* __restrict__ wht,
                 const float* __restrict__ b0, const float* __restrict__ bh,
                 const float* __restrict__ zws) {
    __shared__ alignas(16) u16 sA[128*64];       // 16 KB: A tile 128 rows x 64 k
    __shared__ alignas(16) u16 sB[4][32*64];     // 16 KB: B tile 4 ops x 32 n x 64 k
    const int t = threadIdx.x;
    const int lane = t & 63, wid = t >> 6;       // wid 0..7
    const int l15 = lane & 15, lk = lane >> 4;
    const int mq = wid & 3, nh = wid >> 2;

    const int bid  = blockIdx.x;
    const int slot = bid & 7;
    const int q    = bid >> 3;                   // 0..63
    const int m0   = (q & 15) * 128;             // 16 m-tiles
    const int n0   = ((q >> 4) * 8 + slot) * 32; // 32 n-tiles, 4 per XCD

    // staging lane geometry: lane L -> row_in_chunk = L>>3, LDS slot = L&7,
    // fetch global chunk sc = (L&7) ^ (L>>3)   (XOR swizzle for conflict-free reads)
    const int srow = lane >> 3;
    const int sc   = (lane & 7) ^ srow;
    const int bop = wid >> 1, bhalf = wid & 1;   // B staging role: op, 16-row half

    f32x4 acc[2][4] = {};     // [mfrag][op], reset per edge
    float outv[2][4] = {};    // z-mixed running sum over edges
    const int colw = n0 + nh*16 + l15;

    for (int ck = 0; ck < stepi; ++ck) {
        const u16* Ap; int ldA, nks;
        const u16* Wt; int ldW;
        const float* bias;
        if (ck == 0) {
            Ap = x16; ldA = KPAD0; nks = KPAD0/64;
            Wt = w0t + (size_t)((stepi-1)*4) * HIDDEN * KPAD0; ldW = KPAD0;
            bias = b0 + (size_t)(stepi*5) * HIDDEN;
        } else {
            Ap = acc16 + (size_t)(ck-1) * BATCH * HIDDEN; ldA = HIDDEN; nks = HIDDEN/64;
            int eidx = D_PREF[ck] + (stepi - ck - 1);
            Wt = wht + (size_t)(eidx*4) * HIDDEN * HIDDEN; ldW = HIDDEN;
            bias = bh + (size_t)(((ck-1)*6 + stepi)*5) * HIDDEN;
        }
        // A: 8 waves cover 128 rows (wave wid stages rows wid*16 .. wid*16+15, 2 issues)
        const u16* aG0 = Ap + (size_t)(m0 + wid*16 + srow)     * ldA + sc*8;
        const u16* aG1 = Ap + (size_t)(m0 + wid*16 + 8 + srow) * ldA + sc*8;
        // B: wave wid stages op wid>>1, 16-row half wid&1 (2 issues)
        const u16* Wop = Wt + (size_t)bop * HIDDEN * ldW;
        const u16* bG0 = Wop + (size_t)(n0 + bhalf*16 + srow)     * ldW + sc*8;
        const u16* bG1 = Wop + (size_t)(n0 + bhalf*16 + 8 + srow) * ldW + sc*8;

        for (int kb = 0; kb < nks; ++kb) {
            const int koff = kb * 64;
            gll16(aG0 + koff, &sA[(wid*2)   * 512]);
            gll16(aG1 + koff, &sA[(wid*2+1) * 512]);
            gll16(bG0 + koff, &sB[bop][(bhalf*2)   * 512]);
            gll16(bG1 + koff, &sB[bop][(bhalf*2+1) * 512]);
            __syncthreads();
            #pragma unroll
            for (int kc = 0; kc < 2; ++kc) {
                f16x8 af[2], bf[4];
                #pragma unroll
                for (int f = 0; f < 2; ++f) {
                    int row = mq*32 + f*16 + l15;
                    int cc = (kc*4 + lk) ^ (row & 7);
                    af[f] = *(const f16x8*)&sA[row*64 + cc*8];
                }
                #pragma unroll
                for (int o = 0; o < 4; ++o) {
                    int row = nh*16 + l15;
                    int cc = (kc*4 + lk) ^ (row & 7);
                    bf[o] = *(const f16x8*)&sB[o][row*64 + cc*8];
                }
                #pragma unroll
                for (int o = 0; o < 4; ++o)
                    #pragma unroll
                    for (int f = 0; f < 2; ++f)
                        acc[f][o] = __builtin_amdgcn_mfma_f32_16x16x32_f16(af[f], bf[o], acc[f][o], 0, 0, 0);
            }
            __syncthreads();
        }

        // per-edge epilogue: bias + activation + z-mix, in registers
        const float* zp = zws + (ck*6 + stepi)*5;
        #pragma unroll
        for (int o = 0; o < 4; ++o) {
            float zv = zp[o];
            float bv = bias[(size_t)o*HIDDEN + colw];
            #pragma unroll
            for (int f = 0; f < 2; ++f)
                #pragma unroll
                for (int r = 0; r < 4; ++r) {
                    float pre = acc[f][o][r] + bv;
                    float a;
                    if      (o == 0) a = tanhf(pre);
                    else if (o == 1) a = fmaxf(pre, 0.f);
                    else if (o == 2) a = (pre > 0.f) ? pre : expm1f(pre);
                    else             a = (pre > 0.f) ? pre : 0.01f * pre;
                    outv[f][r] += zv * a;
                    acc[f][o][r] = 0.f;
                }
        }
    }

    // store node output: f16 (A for later steps) or f32 (node 5, feeds out_kernel)
    if (stepi < 5) {
        #pragma unroll
        for (int f = 0; f < 2; ++f)
            #pragma unroll
            for (int r = 0; r < 4; ++r) {
                f16 h = (f16)outv[f][r];
                acc16out[(size_t)(m0 + mq*32 + f*16 + lk*4 + r)*HIDDEN + colw] = __builtin_bit_cast(u16, h);
            }
    } else {
        #pragma unroll
        for (int f = 0; f < 2; ++f)
            #pragma unroll
            for (int r = 0; r < 4; ++r)
                accf5[(size_t)(m0 + mq*32 + f*16 + lk*4 + r)*HIDDEN + colw] = outv[f][r];
    }
}

// ---------------- out = tanh(acc5_f32 @ Wout + bout) ----------------
__global__ void out_kernel(const float* __restrict__ acc5, const float* __restrict__ Wout,
                           const float* __restrict__ bout, float* __restrict__ out) {
    int t = threadIdx.x;
    int g = t & 15, rl = t >> 4;
    int row = blockIdx.x * 16 + rl;
    const float* a = acc5 + (size_t)row * HIDDEN;
    float s[OUT_DIM] = {};
    for (int kk = 0; kk < HIDDEN/16; ++kk) {
        int kidx = kk*16 + g;
        float av = a[kidx];
        const float* wr = Wout + (size_t)kidx * OUT_DIM;
        #pragma unroll
        for (int j = 0; j < OUT_DIM; ++j) s[j] += av * wr[j];
    }
    #pragma unroll
    for (int m = 1; m < 16; m <<= 1) {
        #pragma unroll
        for (int j = 0; j < OUT_DIM; ++j) s[j] += __shfl_xor(s[j], m, 64);
    }
    if (g == 0) {
        #pragma unroll
        for (int j = 0; j < OUT_DIM; ++j)
            out[(size_t)row*OUT_DIM + j] = tanhf(s[j] + bout[j]);
    }
}

extern "C" void kernel_launch(void* const* d_in, const int* in_sizes, int n_in,
                              void* d_out, int out_size, void* d_ws, size_t ws_size,
                              hipStream_t stream) {
    const float* x    = (const float*)d_in[0];
    const float* W0   = (const float*)d_in[1];
    const float* b0   = (const float*)d_in[2];
    const float* Wh   = (const float*)d_in[3];
    const float* bh   = (const float*)d_in[4];
    const float* Wout = (const float*)d_in[5];
    const float* bout = (const float*)d_in[6];
    const float* la   = (const float*)d_in[7];
    const float* eps  = (const float*)d_in[8];
    float* out = (float*)d_out;

    char* ws = (char*)d_ws;
    float* zws  = (float*)(ws + WS_Z);
    u16* x16    = (u16*)(ws + WS_X16);
    u16* acc16  = (u16*)(ws + WS_ACC16);
    float* accf = (float*)(ws + WS_ACCF);
    u16* w0t    = (u16*)(ws + WS_W0T);
    u16* wht    = (u16*)(ws + WS_WHT);

    z_kernel<<<1, 32, 0, stream>>>(la, eps, zws);
    xcvt_kernel<<<(BATCH*KPAD0)/256, 256, 0, stream>>>(x, x16);
    wtrans_kernel<<<1920 + 10240, 256, 0, stream>>>(W0, Wh, w0t, wht);

    for (int i = 1; i <= 5; ++i) {
        u16* a16o = acc16 + (size_t)(i-1)*BATCH*HIDDEN;   // unused for i==5
        step_kernel<<<512, 512, 0, stream>>>(
            i, x16, acc16, a16o, accf, w0t, wht, b0, bh, zws);
    }
    out_kernel<<<BATCH/16, 256, 0, stream>>>(accf, Wout, bout, out);
}